// Round 8
// baseline (274.925 us; speedup 1.0000x reference)
//
#include <hip/hip_runtime.h>
#include <cstdint>
#include <cstddef>

#define T_LEN 8192
#define BATCH 64
#define HID   10
#define CH    66
#define EEG   64
#define SM_STRIDE 8384   // 192-entry zero pad + 8192 live, per batch (16B-aligned stride)
#define CHK   512        // live t per block
#define TS2   548        // yt stride floats: 32 warm + 512 live + 4 pad
#define TCOLS 544        // staged t per channel row (32 warm + 512 live) = 2176 B
#define TILE_B (8 * TCOLS * 4)   // 8-channel tile = 17408 B = 17 x 1024 B

// ---------------------------------------------------------------------------
// K12: FUSED front projection + front LIF, v5 (global_load_lds staging).
// Round-5/7 evidence: VGPR-staged loads cap at ~1.3 KB in flight per CU
// (measured 881 GB/s, latency-bound); pushing depth through VGPRs either
// spills (r4: VGPR 256) or is neutral (r7). Fix: stage x into LDS via
// __builtin_amdgcn_global_load_lds (width 16) -- DMA queue holds 17 KB in
// flight PER WAVE with zero VGPR cost (the +67% GEMM staging lever).
//  - 8-channel tiles: 8 x 2176 B = 17408 B = exactly 17 wave-instructions of
//    1024 B. LDS dest linear (HW: uniform base + lane*16); per-lane GLOBAL
//    address handles the channel-row straddle (c = o/2176).
//  - double-buffered tiles (34 KB); total LDS 58.4 KB -> 2 blocks/CU;
//    in-flight ~34 KB/CU >> ~6 KB needed for full HBM BW.
//  - consume: partial-accumulate into yt, ascending-c fmaf chain IDENTICAL
//    to all prior rounds (tile n resumes from yt) -> y, smask bit-identical.
// Phase B (LIF scan) unchanged from round 7.
// ---------------------------------------------------------------------------
__global__ __launch_bounds__(256, 4) void k_front_lif(
    const float* __restrict__ x, const float* __restrict__ wf_g,
    const float* __restrict__ bf_g, unsigned short* __restrict__ smask,
    float* __restrict__ out) {
    __shared__ float wf[EEG][12];       // wf[c][h], h-padded to 12
    __shared__ float bf[HID];
    __shared__ float yt[HID][TS2];      // y tile, index k <-> t = t0 - 32 + k
    __shared__ float xs[2][8][TCOLS];   // staged x, double-buffered 8-ch tiles
    int tid  = threadIdx.x;
    int wid  = tid >> 6;
    int lane = tid & 63;

    for (int i = tid; i < EEG * 12; i += 256) {
        int c = i / 12, h = i - 12 * (i / 12);
        wf[c][h] = (h < HID) ? wf_g[h * EEG + c] : 0.f;   // w_front layout (H, C)
    }
    if (tid < HID) bf[tid] = bf_g[tid];

    int chunk = blockIdx.x;             // 0..15 (512 live t each)
    int b     = blockIdx.y;             // 0..63
    if (chunk == 0) {                   // zero the 192-entry smask pad for this batch
        for (int i = tid; i < 96; i += 256)
            ((unsigned*)(smask + (size_t)b * SM_STRIDE))[i] = 0u;
        if (b == 0)                     // fold the out-memset dispatch in here
            for (int i = tid; i < BATCH * 2; i += 256) out[i] = 0.f;
    }

    int t0 = chunk * CHK;
    const float* xb = x + ((size_t)b * CH + 1) * T_LEN;   // skip aud channel 0
    // tile base in t: t0-32 (chunk 0 reads 128 B of channel-0 tail -- valid
    // memory; the k<32 region it produces is never read by Phase B there).
    const char* xt = (const char*)(xb + (t0 - 32));

    auto stage = [&](int tile, int bsel) {
        const char* gt = xt + (size_t)tile * 8 * (T_LEN * 4);
        char* lb = (char*)&xs[bsel][0][0];
        for (int s = wid; s < 17; s += 4) {          // 17 x 1024 B per tile
            int o   = s * 1024 + lane * 16;          // linear byte off in tile
            int c   = o / 2176;                      // channel row (0..7)
            int rem = o - c * 2176;                  // byte off within row
            __builtin_amdgcn_global_load_lds(
                (const __attribute__((address_space(1))) void*)
                    (gt + (size_t)c * (T_LEN * 4) + rem),
                (__attribute__((address_space(3))) void*)(lb + s * 1024),
                16, 0, 0);
        }
    };

    // ---- Phase A: stage + consume, 8 tiles, double-buffered ----
    stage(0, 0);
    __syncthreads();                    // drains tile-0 DMA; syncs wf/bf too
    for (int n = 0; n < 8; ++n) {
        int bsel = n & 1;
        if (n < 7) stage(n + 1, bsel ^ 1);   // in flight during consume
        for (int idx = tid; idx < 272; idx += 256) {   // 272 t-col pairs
            int k = idx * 2;
            float2 xc[8];
#pragma unroll
            for (int j = 0; j < 8; ++j) xc[j] = *(const float2*)&xs[bsel][j][k];
            float a0[HID], a1[HID];
            if (n == 0) {
#pragma unroll
                for (int h = 0; h < HID; ++h) { a0[h] = bf[h]; a1[h] = bf[h]; }
            } else {
#pragma unroll
                for (int h = 0; h < HID; ++h) {
                    float2 p = *(const float2*)&yt[h][k];
                    a0[h] = p.x; a1[h] = p.y;
                }
            }
#pragma unroll
            for (int j = 0; j < 8; ++j) {
                int c = n * 8 + j;
                float4 w0 = *(const float4*)&wf[c][0];
                float4 w1 = *(const float4*)&wf[c][4];
                float2 w2 = *(const float2*)&wf[c][8];
                float2 xv = xc[j];
                a0[0] = fmaf(xv.x, w0.x, a0[0]);  a1[0] = fmaf(xv.y, w0.x, a1[0]);
                a0[1] = fmaf(xv.x, w0.y, a0[1]);  a1[1] = fmaf(xv.y, w0.y, a1[1]);
                a0[2] = fmaf(xv.x, w0.z, a0[2]);  a1[2] = fmaf(xv.y, w0.z, a1[2]);
                a0[3] = fmaf(xv.x, w0.w, a0[3]);  a1[3] = fmaf(xv.y, w0.w, a1[3]);
                a0[4] = fmaf(xv.x, w1.x, a0[4]);  a1[4] = fmaf(xv.y, w1.x, a1[4]);
                a0[5] = fmaf(xv.x, w1.y, a0[5]);  a1[5] = fmaf(xv.y, w1.y, a1[5]);
                a0[6] = fmaf(xv.x, w1.z, a0[6]);  a1[6] = fmaf(xv.y, w1.z, a1[6]);
                a0[7] = fmaf(xv.x, w1.w, a0[7]);  a1[7] = fmaf(xv.y, w1.w, a1[7]);
                a0[8] = fmaf(xv.x, w2.x, a0[8]);  a1[8] = fmaf(xv.y, w2.x, a1[8]);
                a0[9] = fmaf(xv.x, w2.y, a0[9]);  a1[9] = fmaf(xv.y, w2.y, a1[9]);
            }
#pragma unroll
            for (int h = 0; h < HID; ++h)
                *(float2*)&yt[h][k] = make_float2(a0[h], a1[h]);
        }
        __syncthreads();               // drains next tile's DMA + syncs yt
    }

    // ---- Phase B: LIF scan, one 128-step quarter per wave, 32-step warm ----
    int h  = lane & 15;
    int hh = h < HID ? h : HID - 1;    // spare lanes duplicate h=9 (bits masked)

    int kliv = 32 + 128 * wid;                       // first live tile index
    int wl   = (chunk == 0 && wid == 0) ? 0 : 32;    // warm length
    int ks   = kliv - wl;                            // scan start (mult of 4)
    int nf   = (128 + wl) >> 2;                      // float4 steps (32 or 40)
    const float4* yrow = (const float4*)&yt[hh][0];
    int base = ks >> 2;

    unsigned short* smb = smask + (size_t)b * SM_STRIDE + 192 + t0 + 128 * wid;
    float u = 0.f, o = 0.f;
    float4 A = yrow[base], B = yrow[base + 1], C = yrow[base + 2];
    for (int f = 0; f < nf; ++f) {
        int nx = f + 3; if (nx > nf - 1) nx = nf - 1;
        float4 D = yrow[base + nx];
        float vv[4] = {A.x, A.y, A.z, A.w};
        int kb = ks + 4 * f;
#pragma unroll
        for (int k2 = 0; k2 < 4; ++k2) {
            u = (o > 0.5f) ? vv[k2] : fmaf(0.25f, u, vv[k2]);   // 0.25*u exact
            bool sp = (u > 0.2f);
            o = sp ? 1.0f : 0.0f;
            unsigned long long bal = __ballot(sp);
            int k = kb + k2;
            if (k >= kliv && h == 0)
                smb[k - kliv] = (unsigned short)(bal & 0x3FFull);
        }
        A = B; B = C; C = D;
    }
}

// ---------------------------------------------------------------------------
// K3: LSNN scan + classifier. 128 chunks x 64 live steps, warm 192 (zero pad
// -> uniform 256-step loop). Direct 1024x22 subset-sum table D (88 KB LDS):
// every rec/X/P lookup is a single ds_read_b32. Unchanged (verified); kept
// stable for attribution.
// ---------------------------------------------------------------------------
__global__ __launch_bounds__(512) void k_lsnn(
    const unsigned short* __restrict__ smask,
    const float* __restrict__ w_in, const float* __restrict__ w_rec,
    const float* __restrict__ w_cls, const float* __restrict__ b_cls,
    float* __restrict__ out) {
    extern __shared__ float LDSBUF[];
    float* T = LDSBUF;          // [1536]: [hi*768 + m*24 + role]
    float* D = LDSBUF + 1536;   // [1024*22]: full 10-bit subset sums
    int tid = threadIdx.x;
    for (int i = tid; i < 1536; i += 512) {
        int hi = i / 768;
        int rem = i - hi * 768;
        int m = rem / 24, role = rem - m * 24;
        float s = 0.f;
        if (role < 22) {
            const float* wrow = (role < 10) ? (w_in + role * HID)
                              : (role < 12) ? (w_cls + (role - 10) * HID)
                                            : (w_rec + (role - 12) * HID);
#pragma unroll
            for (int j = 0; j < 5; ++j)
                if (m & (1u << j)) s += wrow[hi * 5 + j];
        }
        T[i] = s;
    }
    __syncthreads();
    for (int i = tid; i < 1024 * 22; i += 512) {
        int z = i / 22, role = i - z * 22;
        D[i] = T[(z & 31) * 24 + role] + T[768 + (z >> 5) * 24 + role];
    }
    __syncthreads();

    int lane = tid & 63;
    int q = lane >> 4;                 // unit-in-wave 0..3
    int r = lane & 15;                 // role: 0..9 hidden, 10..11 cls, 12..15 shadow
    int rr = r < 12 ? r : 11;          // X/P table role (shadows duplicate 11)
    int rrec = 12 + (r < HID ? r : 9); // rec table role
    int shq = q * 16;
    int id = blockIdx.x * 32 + (tid >> 4);   // 256*32 = 8192 units, no tail
    int b = id >> 7, chunk = id & 127;

    float bcl = (r == 10 || r == 11) ? b_cls[r - HID] : 0.f;

    const unsigned short* sm = smask + (size_t)b * SM_STRIDE + (size_t)chunk * 64;

    auto xlook = [&](const uint4& mv, float* X) {
        unsigned hw[8] = { mv.x & 0x3FFu, (mv.x >> 16) & 0x3FFu,
                           mv.y & 0x3FFu, (mv.y >> 16) & 0x3FFu,
                           mv.z & 0x3FFu, (mv.z >> 16) & 0x3FFu,
                           mv.w & 0x3FFu, (mv.w >> 16) & 0x3FFu };
#pragma unroll
        for (int u = 0; u < 8; ++u)
            X[u] = D[hw[u] * 22 + rr];
    };

    // 4-deep mask prefetch ring
    uint4 mB = *(const uint4*)(sm + 8);
    uint4 mC = *(const uint4*)(sm + 16);
    uint4 mD = *(const uint4*)(sm + 24);
    float Xc[8], Xn[8], Pc[8], Pn[8];
    { uint4 m0 = *(const uint4*)(sm); xlook(m0, Xc); }
#pragma unroll
    for (int u = 0; u < 8; ++u) { Pc[u] = 0.f; Pn[u] = 0.f; }

    float v = 0.f, cur = 0.f;
    unsigned zmask = 0;
    float uc = 0.f, oc = 0.f, accs = 0.f;

    for (int gr = 0; gr < 32; ++gr) {
        int nb = gr + 4; if (nb > 31) nb = 31;
        uint4 mE = *(const uint4*)(sm + (size_t)nb * 8);
        xlook(mB, Xn);                  // x_in for next group (off-chain)
        unsigned zs[8];
#pragma unroll
        for (int u = 0; u < 8; ++u) {
            float rec = D[zmask * 22 + rrec];
            float ij = (cur + Xc[u]) + rec;
            float vd = v + 0.1f * (ij - v);     // bit-exact form
            cur = ij - 0.2f * ij;               // bit-exact form
            bool zb = vd > 0.2f;                // b_dec == VTH exactly
            unsigned long long bal = __ballot(zb);
            v = zb ? 0.f : vd;
            zmask = (unsigned)(bal >> shq) & 0x3FFu;
            zs[u] = zmask;
        }
        if (gr >= 21) {                        // classifier-input lookups
#pragma unroll
            for (int u = 0; u < 8; ++u)
                Pn[u] = D[zs[u] * 22 + rr];
        }
        if (gr >= 22) {                        // classifier LIF for group gr-1
            bool in = (gr >= 25);              // live groups are 24..31
#pragma unroll
            for (int u = 0; u < 8; ++u) {
                float ci = Pc[u] + bcl;
                uc = (oc > 0.5f) ? ci : fmaf(0.25f, uc, ci);
                oc = (uc > 0.2f) ? 1.f : 0.f;
                if (in) accs += oc;
            }
        }
#pragma unroll
        for (int u = 0; u < 8; ++u) { Xc[u] = Xn[u]; Pc[u] = Pn[u]; }
        mB = mC; mC = mD; mD = mE;
    }
    // epilogue: classifier for group 31 (live)
#pragma unroll
    for (int u = 0; u < 8; ++u) {
        float ci = Pc[u] + bcl;
        uc = (oc > 0.5f) ? ci : fmaf(0.25f, uc, ci);
        oc = (uc > 0.2f) ? 1.f : 0.f;
        accs += oc;
    }
    if (r == 10 || r == 11)
        atomicAdd(&out[b * 2 + (r - 10)], accs * (1.0f / 8192.0f));
}

// ---------------------------------------------------------------------------
extern "C" void kernel_launch(void* const* d_in, const int* in_sizes, int n_in,
                              void* d_out, int out_size, void* d_ws, size_t ws_size,
                              hipStream_t stream) {
    const float* x       = (const float*)d_in[0];
    const float* w_front = (const float*)d_in[1];
    const float* b_front = (const float*)d_in[2];
    const float* w_in    = (const float*)d_in[3];
    const float* w_rec   = (const float*)d_in[4];
    const float* w_cls   = (const float*)d_in[5];
    const float* b_cls   = (const float*)d_in[6];
    float* out = (float*)d_out;

    unsigned short* smask = (unsigned short*)d_ws;   // 64*8384*2 = 1.07 MB

    k_front_lif<<<dim3(16, BATCH), 256, 0, stream>>>(x, w_front, b_front, smask, out);
    k_lsnn<<<dim3(256), 512, (1536 + 1024 * 22) * sizeof(float), stream>>>(
        smask, w_in, w_rec, w_cls, b_cls, out);
}